// Round 1
// baseline (485.306 us; speedup 1.0000x reference)
//
#include <hip/hip_runtime.h>
#include <math.h>

#define AS1 __attribute__((address_space(1)))
#define AS3 __attribute__((address_space(3)))

typedef __attribute__((ext_vector_type(8))) short short8;
typedef __attribute__((ext_vector_type(4))) float f32x4;

static __device__ __forceinline__ unsigned short f2bf(float f) {
    unsigned u = __float_as_uint(f);
    unsigned r = (u + 0x7fffu + ((u >> 16) & 1u)) >> 16;
    return (unsigned short)r;
}

// ---------------- f32 -> bf16 convert (vectorized x4) ----------------
__global__ __launch_bounds__(256) void cvt_f32_bf16(const float* __restrict__ src,
                                                    unsigned short* __restrict__ dst,
                                                    int n4) {
    int i = blockIdx.x * 256 + threadIdx.x;
    int stride = gridDim.x * 256;
    for (; i < n4; i += stride) {
        float4 v = ((const float4*)src)[i];
        ushort4 o;
        o.x = f2bf(v.x); o.y = f2bf(v.y); o.z = f2bf(v.z); o.w = f2bf(v.w);
        ((ushort4*)dst)[i] = o;
    }
}

// extract ts (cols 0..127 of ssm_p, row stride 160) -> dense bf16 1024x128
__global__ __launch_bounds__(256) void cvt_ts(const float* __restrict__ ssmp,
                                              unsigned short* __restrict__ ts) {
    int i = blockIdx.x * 256 + threadIdx.x;   // < 32768
    int t = i >> 5, c4 = (i & 31) * 4;
    float4 v = *(const float4*)&ssmp[t * 160 + c4];
    ushort4 o;
    o.x = f2bf(v.x); o.y = f2bf(v.y); o.z = f2bf(v.z); o.w = f2bf(v.w);
    *(ushort4*)&ts[t * 128 + c4] = o;
}

// ---------------- depthwise causal conv (K=4) + bias + silu ----------------
__global__ __launch_bounds__(256) void conv_silu(const float* __restrict__ h,
                                                 const float* __restrict__ cw,
                                                 const float* __restrict__ cb,
                                                 float* __restrict__ hc_f,
                                                 unsigned short* __restrict__ hc_bf) {
    int idx = blockIdx.x * 256 + threadIdx.x;   // < 1024*4096
    int d = idx & 4095, t = idx >> 12;
    float acc = cb[d];
    float4 w = *(const float4*)&cw[d * 4];
    const float* wp = (const float*)&w;
#pragma unroll
    for (int k = 0; k < 4; ++k) {
        int tt = t + k - 3;
        if (tt >= 0) acc += h[tt * 4096 + d] * wp[k];
    }
    float s = acc / (1.f + __expf(-acc));   // silu
    hc_f[idx] = s;
    hc_bf[idx] = f2bf(s);
}

// ---------------- bf16 MFMA GEMM:  C(M,N) = A(M,K) @ B(N,K)^T ----------------
// 256 threads = 4 waves (2x2), tile BM x 128, BK=32, 16x16x32 MFMA.
enum { EPI_PLAIN = 0, EPI_SPLIT = 1, EPI_ATOMIC = 2, EPI_SOFTPLUS = 3 };

template <int BM, int EPI>
__global__ __launch_bounds__(256)
void gemm_bt(const short* __restrict__ A, const short* __restrict__ B,
             float* __restrict__ C, float* __restrict__ C2,
             const float* __restrict__ bias,
             int M, int N, int K, int ldc, int kcLen) {
    __shared__ short A_lds[BM * 32];
    __shared__ short B_lds[128 * 32];
    const int tid = threadIdx.x;
    const int wv = tid >> 6, ln = tid & 63;
    const int lr = ln & 15, kg = ln >> 4;
    const int m0 = blockIdx.y * BM;
    const int n0 = blockIdx.x * 128;
    const int kbeg = blockIdx.z * kcLen;
    const int kend = kbeg + kcLen;
    const int wm = wv >> 1, wn = wv & 1;
    constexpr int MR = BM / 32;

    f32x4 acc[MR][4];
#pragma unroll
    for (int mi = 0; mi < MR; ++mi)
#pragma unroll
        for (int ni = 0; ni < 4; ++ni) acc[mi][ni] = (f32x4){0.f, 0.f, 0.f, 0.f};

    const int arow = tid >> 2;        // 0..63
    const int kq8 = (tid & 3) * 8;    // bf16 offset within 32-wide K step

    for (int k0 = kbeg; k0 < kend; k0 += 32) {
#pragma unroll
        for (int r = 0; r < BM / 64; ++r) {
            const short* srcA = A + (size_t)(m0 + r * 64 + arow) * K + (k0 + kq8);
            short* dstA = &A_lds[(r * 64 + wv * 16) * 32];
            __builtin_amdgcn_global_load_lds((const AS1 void*)srcA, (AS3 void*)dstA, 16, 0, 0);
        }
#pragma unroll
        for (int r = 0; r < 2; ++r) {
            int brow = n0 + r * 64 + arow;
            if (brow > N - 1) brow = N - 1;   // clamp (N=160 case); garbage cols masked at store
            const short* srcB = B + (size_t)brow * K + (k0 + kq8);
            short* dstB = &B_lds[(r * 64 + wv * 16) * 32];
            __builtin_amdgcn_global_load_lds((const AS1 void*)srcB, (AS3 void*)dstB, 16, 0, 0);
        }
        __syncthreads();

        short8 av[MR], bv[4];
#pragma unroll
        for (int mi = 0; mi < MR; ++mi)
            av[mi] = *(const short8*)&A_lds[(wm * (BM / 2) + mi * 16 + lr) * 32 + kg * 8];
#pragma unroll
        for (int ni = 0; ni < 4; ++ni)
            bv[ni] = *(const short8*)&B_lds[(wn * 64 + ni * 16 + lr) * 32 + kg * 8];
#pragma unroll
        for (int mi = 0; mi < MR; ++mi)
#pragma unroll
            for (int ni = 0; ni < 4; ++ni)
                acc[mi][ni] = __builtin_amdgcn_mfma_f32_16x16x32_bf16(av[mi], bv[ni], acc[mi][ni], 0, 0, 0);
        __syncthreads();
    }

#pragma unroll
    for (int mi = 0; mi < MR; ++mi) {
        int crow0 = m0 + wm * (BM / 2) + mi * 16 + kg * 4;
#pragma unroll
        for (int ni = 0; ni < 4; ++ni) {
            int ccol = n0 + wn * 64 + ni * 16 + lr;
#pragma unroll
            for (int i = 0; i < 4; ++i) {
                float v = acc[mi][ni][i];
                size_t crow = (size_t)(crow0 + i);
                if constexpr (EPI == EPI_PLAIN) {
                    C[crow * ldc + ccol] = v;
                } else if constexpr (EPI == EPI_SPLIT) {
                    if (ccol < 4096) C[crow * 4096 + ccol] = v;
                    else C2[crow * 4096 + (ccol - 4096)] = v;
                } else if constexpr (EPI == EPI_ATOMIC) {
                    if (ccol < N) atomicAdd(&C[crow * ldc + ccol], v);
                } else {   // EPI_SOFTPLUS: softplus(v + bias[n])
                    float x = v + bias[ccol];
                    C[crow * ldc + ccol] = fmaxf(x, 0.f) + log1pf(__expf(-fabsf(x)));
                }
            }
        }
    }
}

// ---------------- selective scan, fused epilogue ----------------
// block: 256 threads = 16 d x 16 n; grid 256 blocks (d tiles of 16).
#define TC 64
__global__ __launch_bounds__(256) void scan_kernel(const float* __restrict__ dt,
                                                   const float* __restrict__ hc,
                                                   const float* __restrict__ ssmp,
                                                   const float* __restrict__ A_log,
                                                   const float* __restrict__ Dp,
                                                   const float* __restrict__ gate,
                                                   unsigned short* __restrict__ y_bf) {
    const int tid = threadIdx.x;
    const int n = tid & 15, dl = tid >> 4;
    const int d0 = blockIdx.x * 16;
    const int d = d0 + dl;

    const float Acoef = -__expf(A_log[d * 16 + n]);
    const float Dcoef = Dp[d];
    float state = 0.f;

    __shared__ float s_dt[TC][16], s_hc[TC][16], s_gt[TC][16];
    __shared__ float s_B[TC][16], s_C[TC][16], s_y[TC][16];

    for (int t0 = 0; t0 < 1024; t0 += TC) {
        for (int i = tid; i < TC * 16; i += 256) {
            int tt = i >> 4, dd = i & 15;
            int g = (t0 + tt) * 4096 + d0 + dd;
            s_dt[tt][dd] = dt[g];
            s_hc[tt][dd] = hc[g];
            s_gt[tt][dd] = gate[g];
            s_B[tt][dd] = ssmp[(t0 + tt) * 160 + 128 + dd];
            s_C[tt][dd] = ssmp[(t0 + tt) * 160 + 144 + dd];
        }
        __syncthreads();
        for (int tt = 0; tt < TC; ++tt) {
            float dtv = s_dt[tt][dl];
            float hcv = s_hc[tt][dl];
            float dA = __expf(dtv * Acoef);
            state = dA * state + dtv * hcv * s_B[tt][n];
            float c = state * s_C[tt][n];
            c += __shfl_xor(c, 1, 64);
            c += __shfl_xor(c, 2, 64);
            c += __shfl_xor(c, 4, 64);
            c += __shfl_xor(c, 8, 64);
            if (n == 0) {
                float g = s_gt[tt][dl];
                float yv = (c + hcv * Dcoef) * (g / (1.f + __expf(-g)));
                s_y[tt][dl] = yv;
            }
        }
        __syncthreads();
        for (int i = tid; i < TC * 16; i += 256) {
            int tt = i >> 4, dd = i & 15;
            y_bf[(t0 + tt) * 4096 + d0 + dd] = f2bf(s_y[tt][dd]);
        }
        __syncthreads();
    }
}

// ---------------- launch ----------------
extern "C" void kernel_launch(void* const* d_in, const int* in_sizes, int n_in,
                              void* d_out, int out_size, void* d_ws, size_t ws_size,
                              hipStream_t stream) {
    (void)in_sizes; (void)n_in; (void)out_size; (void)ws_size;
    const float* hidden = (const float*)d_in[0];   // 1x1024x2048
    const float* W_in   = (const float*)d_in[1];   // 8192x2048
    const float* conv_w = (const float*)d_in[2];   // 4096x1x4
    const float* conv_b = (const float*)d_in[3];   // 4096
    const float* W_x    = (const float*)d_in[4];   // 160x4096
    const float* W_dt   = (const float*)d_in[5];   // 4096x128
    const float* b_dt   = (const float*)d_in[6];   // 4096
    const float* A_log  = (const float*)d_in[7];   // 4096x16
    const float* D_p    = (const float*)d_in[8];   // 4096
    const float* W_out  = (const float*)d_in[9];   // 2048x4096
    float* out = (float*)d_out;                    // 1024x2048

    char* w = (char*)d_ws;
    unsigned short* hid_bf = (unsigned short*)w;  w += (size_t)1024 * 2048 * 2;
    unsigned short* Wbig   = (unsigned short*)w;  w += (size_t)8192 * 2048 * 2;  // W_in, later W_out
    float* h_buf           = (float*)w;           w += (size_t)1024 * 4096 * 4;  // h, later dt
    float* gate            = (float*)w;           w += (size_t)1024 * 4096 * 4;
    float* hc_f            = (float*)w;           w += (size_t)1024 * 4096 * 4;
    unsigned short* hc_bf  = (unsigned short*)w;  w += (size_t)1024 * 4096 * 2;
    float* ssmp            = (float*)w;           w += (size_t)1024 * 160 * 4;
    unsigned short* ts_bf  = (unsigned short*)w;  w += (size_t)1024 * 128 * 2;
    unsigned short* Wx_bf  = (unsigned short*)w;  w += (size_t)160 * 4096 * 2;
    unsigned short* Wdt_bf = (unsigned short*)w;  w += (size_t)4096 * 128 * 2;
    unsigned short* y_bf   = (unsigned short*)w;  w += (size_t)1024 * 4096 * 2;

    hipMemsetAsync(ssmp, 0, (size_t)1024 * 160 * 4, stream);

    cvt_f32_bf16<<<2048, 256, 0, stream>>>(hidden, hid_bf, 1024 * 2048 / 4);
    cvt_f32_bf16<<<4096, 256, 0, stream>>>(W_in, Wbig, 8192 * 2048 / 4);
    cvt_f32_bf16<<<640, 256, 0, stream>>>(W_x, Wx_bf, 160 * 4096 / 4);
    cvt_f32_bf16<<<512, 256, 0, stream>>>(W_dt, Wdt_bf, 4096 * 128 / 4);

    // GEMM1: proj = hidden @ W_in^T  -> split h | gate
    gemm_bt<128, EPI_SPLIT><<<dim3(64, 8, 1), 256, 0, stream>>>(
        (const short*)hid_bf, (const short*)Wbig, h_buf, gate, nullptr,
        1024, 8192, 2048, 8192, 2048);

    conv_silu<<<16384, 256, 0, stream>>>(h_buf, conv_w, conv_b, hc_f, hc_bf);

    // reuse Wbig for W_out (after GEMM1 has consumed W_in)
    cvt_f32_bf16<<<2048, 256, 0, stream>>>(W_out, Wbig, 2048 * 4096 / 4);

    // GEMM2: ssm_p = hc @ W_x^T (N=160), split-K x16, atomic f32 accumulate
    gemm_bt<128, EPI_ATOMIC><<<dim3(2, 8, 16), 256, 0, stream>>>(
        (const short*)hc_bf, (const short*)Wx_bf, ssmp, nullptr, nullptr,
        1024, 160, 4096, 160, 256);

    cvt_ts<<<128, 256, 0, stream>>>(ssmp, ts_bf);

    // GEMM3: dt = softplus(ts @ W_dt^T + b_dt)  (writes into h_buf)
    gemm_bt<128, EPI_SOFTPLUS><<<dim3(32, 8, 1), 256, 0, stream>>>(
        (const short*)ts_bf, (const short*)Wdt_bf, h_buf, nullptr, b_dt,
        1024, 4096, 128, 4096, 128);

    // scan + fused (y + hc*D)*silu(gate) -> y_bf
    scan_kernel<<<256, 256, 0, stream>>>(h_buf, hc_f, ssmp, A_log, D_p, gate, y_bf);

    // GEMM4: out = y @ W_out^T
    gemm_bt<64, EPI_PLAIN><<<dim3(16, 16, 1), 256, 0, stream>>>(
        (const short*)y_bf, (const short*)Wbig, out, nullptr, nullptr,
        1024, 2048, 4096, 2048, 4096);
}

// Round 2
// 269.668 us; speedup vs baseline: 1.7996x; 1.7996x over previous
//
#include <hip/hip_runtime.h>
#include <math.h>

#define AS1 __attribute__((address_space(1)))
#define AS3 __attribute__((address_space(3)))

typedef __attribute__((ext_vector_type(8))) short short8;
typedef __attribute__((ext_vector_type(4))) float f32x4;

static __device__ __forceinline__ unsigned short f2bf(float f) {
    unsigned u = __float_as_uint(f);
    unsigned r = (u + 0x7fffu + ((u >> 16) & 1u)) >> 16;
    return (unsigned short)r;
}

// ---------------- f32 -> bf16 convert (vectorized x4) ----------------
__global__ __launch_bounds__(256) void cvt_f32_bf16(const float* __restrict__ src,
                                                    unsigned short* __restrict__ dst,
                                                    int n4) {
    int i = blockIdx.x * 256 + threadIdx.x;
    int stride = gridDim.x * 256;
    for (; i < n4; i += stride) {
        float4 v = ((const float4*)src)[i];
        ushort4 o;
        o.x = f2bf(v.x); o.y = f2bf(v.y); o.z = f2bf(v.z); o.w = f2bf(v.w);
        ((ushort4*)dst)[i] = o;
    }
}

// extract ts (cols 0..127 of ssm_p, row stride 160) -> dense bf16 1024x128
__global__ __launch_bounds__(256) void cvt_ts(const float* __restrict__ ssmp,
                                              unsigned short* __restrict__ ts) {
    int i = blockIdx.x * 256 + threadIdx.x;   // < 32768
    int t = i >> 5, c4 = (i & 31) * 4;
    float4 v = *(const float4*)&ssmp[t * 160 + c4];
    ushort4 o;
    o.x = f2bf(v.x); o.y = f2bf(v.y); o.z = f2bf(v.z); o.w = f2bf(v.w);
    *(ushort4*)&ts[t * 128 + c4] = o;
}

// ---------------- depthwise causal conv (K=4) + bias + silu ----------------
__global__ __launch_bounds__(256) void conv_silu(const float* __restrict__ h,
                                                 const float* __restrict__ cw,
                                                 const float* __restrict__ cb,
                                                 float* __restrict__ hc_f,
                                                 unsigned short* __restrict__ hc_bf) {
    int idx = blockIdx.x * 256 + threadIdx.x;   // < 1024*4096
    int d = idx & 4095, t = idx >> 12;
    float acc = cb[d];
    float4 w = *(const float4*)&cw[d * 4];
    const float* wp = (const float*)&w;
#pragma unroll
    for (int k = 0; k < 4; ++k) {
        int tt = t + k - 3;
        if (tt >= 0) acc += h[tt * 4096 + d] * wp[k];
    }
    float s = acc / (1.f + __expf(-acc));   // silu
    hc_f[idx] = s;
    hc_bf[idx] = f2bf(s);
}

// ---------------- bf16 MFMA GEMM:  C(M,N) = A(M,K) @ B(N,K)^T ----------------
enum { EPI_PLAIN = 0, EPI_SPLIT = 1, EPI_ATOMIC = 2, EPI_SOFTPLUS = 3 };

template <int BM, int EPI>
__global__ __launch_bounds__(256)
void gemm_bt(const short* __restrict__ A, const short* __restrict__ B,
             float* __restrict__ C, float* __restrict__ C2,
             const float* __restrict__ bias,
             int M, int N, int K, int ldc, int kcLen) {
    __shared__ short A_lds[BM * 32];
    __shared__ short B_lds[128 * 32];
    const int tid = threadIdx.x;
    const int wv = tid >> 6, ln = tid & 63;
    const int lr = ln & 15, kg = ln >> 4;
    const int m0 = blockIdx.y * BM;
    const int n0 = blockIdx.x * 128;
    const int kbeg = blockIdx.z * kcLen;
    const int kend = kbeg + kcLen;
    const int wm = wv >> 1, wn = wv & 1;
    constexpr int MR = BM / 32;

    f32x4 acc[MR][4];
#pragma unroll
    for (int mi = 0; mi < MR; ++mi)
#pragma unroll
        for (int ni = 0; ni < 4; ++ni) acc[mi][ni] = (f32x4){0.f, 0.f, 0.f, 0.f};

    const int arow = tid >> 2;        // 0..63
    const int kq8 = (tid & 3) * 8;    // bf16 offset within 32-wide K step

    for (int k0 = kbeg; k0 < kend; k0 += 32) {
#pragma unroll
        for (int r = 0; r < BM / 64; ++r) {
            const short* srcA = A + (size_t)(m0 + r * 64 + arow) * K + (k0 + kq8);
            short* dstA = &A_lds[(r * 64 + wv * 16) * 32];
            __builtin_amdgcn_global_load_lds((const AS1 void*)srcA, (AS3 void*)dstA, 16, 0, 0);
        }
#pragma unroll
        for (int r = 0; r < 2; ++r) {
            int brow = n0 + r * 64 + arow;
            if (brow > N - 1) brow = N - 1;   // clamp (N=160 case); garbage cols masked at store
            const short* srcB = B + (size_t)brow * K + (k0 + kq8);
            short* dstB = &B_lds[(r * 64 + wv * 16) * 32];
            __builtin_amdgcn_global_load_lds((const AS1 void*)srcB, (AS3 void*)dstB, 16, 0, 0);
        }
        __syncthreads();

        short8 av[MR], bv[4];
#pragma unroll
        for (int mi = 0; mi < MR; ++mi)
            av[mi] = *(const short8*)&A_lds[(wm * (BM / 2) + mi * 16 + lr) * 32 + kg * 8];
#pragma unroll
        for (int ni = 0; ni < 4; ++ni)
            bv[ni] = *(const short8*)&B_lds[(wn * 64 + ni * 16 + lr) * 32 + kg * 8];
#pragma unroll
        for (int mi = 0; mi < MR; ++mi)
#pragma unroll
            for (int ni = 0; ni < 4; ++ni)
                acc[mi][ni] = __builtin_amdgcn_mfma_f32_16x16x32_bf16(av[mi], bv[ni], acc[mi][ni], 0, 0, 0);
        __syncthreads();
    }

#pragma unroll
    for (int mi = 0; mi < MR; ++mi) {
        int crow0 = m0 + wm * (BM / 2) + mi * 16 + kg * 4;
#pragma unroll
        for (int ni = 0; ni < 4; ++ni) {
            int ccol = n0 + wn * 64 + ni * 16 + lr;
#pragma unroll
            for (int i = 0; i < 4; ++i) {
                float v = acc[mi][ni][i];
                size_t crow = (size_t)(crow0 + i);
                if constexpr (EPI == EPI_PLAIN) {
                    C[crow * ldc + ccol] = v;
                } else if constexpr (EPI == EPI_SPLIT) {
                    if (ccol < 4096) C[crow * 4096 + ccol] = v;
                    else C2[crow * 4096 + (ccol - 4096)] = v;
                } else if constexpr (EPI == EPI_ATOMIC) {
                    if (ccol < N) atomicAdd(&C[crow * ldc + ccol], v);
                } else {   // EPI_SOFTPLUS: softplus(v + bias[n])
                    float x = v + bias[ccol];
                    C[crow * ldc + ccol] = fmaxf(x, 0.f) + log1pf(__expf(-fabsf(x)));
                }
            }
        }
    }
}

// ================= chunked selective scan =================
// 1024 timesteps -> NCH=64 chunks of CLEN=16.
// Pass1: per (chunk, d) local recurrence from 0; store local end state + sum(dt).
// Pass2: per (d,n) serial combine over chunks -> initial state per chunk (in place).
// Pass3: per (chunk, d) re-run recurrence from correct init; fused y epilogue.
#define CLEN 16
#define NCH 64

__global__ __launch_bounds__(256)
void scan_p1(const float* __restrict__ dt, const float* __restrict__ hc,
             const float* __restrict__ ssmp, const float* __restrict__ A_log,
             float* __restrict__ Sbuf, float* __restrict__ dtsum) {
    const int tid = threadIdx.x;
    const int c = blockIdx.x & (NCH - 1);
    const int db = blockIdx.x >> 6;
    const int d = db * 256 + tid;
    const int t0 = c * CLEN;

    float Ac[16];
#pragma unroll
    for (int i = 0; i < 4; ++i) {
        float4 v = *(const float4*)&A_log[d * 16 + i * 4];
        Ac[i*4+0] = -__expf(v.x); Ac[i*4+1] = -__expf(v.y);
        Ac[i*4+2] = -__expf(v.z); Ac[i*4+3] = -__expf(v.w);
    }

    __shared__ float sB[CLEN][16];
    sB[tid >> 4][tid & 15] = ssmp[(t0 + (tid >> 4)) * 160 + 128 + (tid & 15)];
    __syncthreads();

    float st[16];
#pragma unroll
    for (int n = 0; n < 16; ++n) st[n] = 0.f;
    float ds = 0.f;

    for (int tt = 0; tt < CLEN; ++tt) {
        float dtv = dt[(size_t)(t0 + tt) * 4096 + d];
        float hcv = hc[(size_t)(t0 + tt) * 4096 + d];
        float du = dtv * hcv;
        ds += dtv;
#pragma unroll
        for (int n = 0; n < 16; ++n) {
            float dA = __expf(dtv * Ac[n]);
            st[n] = fmaf(dA, st[n], du * sB[tt][n]);
        }
    }

    float* o = Sbuf + ((size_t)c * 4096 + d) * 16;
#pragma unroll
    for (int i = 0; i < 4; ++i)
        *(float4*)&o[i * 4] = make_float4(st[i*4], st[i*4+1], st[i*4+2], st[i*4+3]);
    dtsum[c * 4096 + d] = ds;
}

__global__ __launch_bounds__(256)
void scan_p2(const float* __restrict__ A_log, const float* __restrict__ dtsum,
             float* __restrict__ S) {
    const int idx = blockIdx.x * 256 + threadIdx.x;   // (d,n), 65536
    const int d = idx >> 4;
    const float Ac = -__expf(A_log[idx]);
    float s = 0.f;
    for (int c = 0; c < NCH; ++c) {
        size_t o = (size_t)c * 65536 + idx;
        float sl = S[o];
        float P = __expf(Ac * dtsum[c * 4096 + d]);
        S[o] = s;                       // initial state for chunk c
        s = fmaf(P, s, sl);
    }
}

__global__ __launch_bounds__(256)
void scan_p3(const float* __restrict__ dt, const float* __restrict__ hc,
             const float* __restrict__ ssmp, const float* __restrict__ A_log,
             const float* __restrict__ Dp, const float* __restrict__ gate,
             const float* __restrict__ Sinit, unsigned short* __restrict__ y_bf) {
    const int tid = threadIdx.x;
    const int c = blockIdx.x & (NCH - 1);
    const int db = blockIdx.x >> 6;
    const int d = db * 256 + tid;
    const int t0 = c * CLEN;

    float Ac[16];
#pragma unroll
    for (int i = 0; i < 4; ++i) {
        float4 v = *(const float4*)&A_log[d * 16 + i * 4];
        Ac[i*4+0] = -__expf(v.x); Ac[i*4+1] = -__expf(v.y);
        Ac[i*4+2] = -__expf(v.z); Ac[i*4+3] = -__expf(v.w);
    }
    const float Dcoef = Dp[d];

    __shared__ float sB[CLEN][16], sC[CLEN][16];
    {
        int tt = tid >> 4, nn = tid & 15;
        sB[tt][nn] = ssmp[(t0 + tt) * 160 + 128 + nn];
        sC[tt][nn] = ssmp[(t0 + tt) * 160 + 144 + nn];
    }
    __syncthreads();

    float st[16];
    {
        const float* si = Sinit + ((size_t)c * 4096 + d) * 16;
#pragma unroll
        for (int i = 0; i < 4; ++i) {
            float4 v = *(const float4*)&si[i * 4];
            st[i*4] = v.x; st[i*4+1] = v.y; st[i*4+2] = v.z; st[i*4+3] = v.w;
        }
    }

    for (int tt = 0; tt < CLEN; ++tt) {
        size_t g = (size_t)(t0 + tt) * 4096 + d;
        float dtv = dt[g];
        float hcv = hc[g];
        float du = dtv * hcv;
        float p[16];
#pragma unroll
        for (int n = 0; n < 16; ++n) {
            float dA = __expf(dtv * Ac[n]);
            st[n] = fmaf(dA, st[n], du * sB[tt][n]);
            p[n] = st[n] * sC[tt][n];
        }
        // tree reduce over n
#pragma unroll
        for (int n = 0; n < 8; ++n) p[n] += p[n + 8];
#pragma unroll
        for (int n = 0; n < 4; ++n) p[n] += p[n + 4];
        p[0] += p[2]; p[1] += p[3];
        float csum = p[0] + p[1];
        float gv = gate[g];
        float yv = (csum + hcv * Dcoef) * (gv / (1.f + __expf(-gv)));
        y_bf[g] = f2bf(yv);
    }
}

// ---------------- launch ----------------
extern "C" void kernel_launch(void* const* d_in, const int* in_sizes, int n_in,
                              void* d_out, int out_size, void* d_ws, size_t ws_size,
                              hipStream_t stream) {
    (void)in_sizes; (void)n_in; (void)out_size; (void)ws_size;
    const float* hidden = (const float*)d_in[0];   // 1x1024x2048
    const float* W_in   = (const float*)d_in[1];   // 8192x2048
    const float* conv_w = (const float*)d_in[2];   // 4096x1x4
    const float* conv_b = (const float*)d_in[3];   // 4096
    const float* W_x    = (const float*)d_in[4];   // 160x4096
    const float* W_dt   = (const float*)d_in[5];   // 4096x128
    const float* b_dt   = (const float*)d_in[6];   // 4096
    const float* A_log  = (const float*)d_in[7];   // 4096x16
    const float* D_p    = (const float*)d_in[8];   // 4096
    const float* W_out  = (const float*)d_in[9];   // 2048x4096
    float* out = (float*)d_out;                    // 1024x2048

    char* w = (char*)d_ws;
    unsigned short* hid_bf = (unsigned short*)w;  w += (size_t)1024 * 2048 * 2;
    unsigned short* Wbig   = (unsigned short*)w;  w += (size_t)8192 * 2048 * 2;  // W_in, later W_out
    float* h_buf           = (float*)w;           w += (size_t)1024 * 4096 * 4;  // h, later dt
    float* gate            = (float*)w;           w += (size_t)1024 * 4096 * 4;
    float* hc_f            = (float*)w;           w += (size_t)1024 * 4096 * 4;
    unsigned short* hc_bf  = (unsigned short*)w;  w += (size_t)1024 * 4096 * 2;
    float* ssmp            = (float*)w;           w += (size_t)1024 * 160 * 4;
    unsigned short* ts_bf  = (unsigned short*)w;  w += (size_t)1024 * 128 * 2;
    unsigned short* Wx_bf  = (unsigned short*)w;  w += (size_t)160 * 4096 * 2;
    unsigned short* Wdt_bf = (unsigned short*)w;  w += (size_t)4096 * 128 * 2;
    unsigned short* y_bf   = (unsigned short*)w;  w += (size_t)1024 * 4096 * 2;
    float* Sbuf            = (float*)w;           w += (size_t)NCH * 4096 * 16 * 4;  // 16 MB
    float* dtsum           = (float*)w;           w += (size_t)NCH * 4096 * 4;       // 1 MB

    hipMemsetAsync(ssmp, 0, (size_t)1024 * 160 * 4, stream);

    cvt_f32_bf16<<<2048, 256, 0, stream>>>(hidden, hid_bf, 1024 * 2048 / 4);
    cvt_f32_bf16<<<4096, 256, 0, stream>>>(W_in, Wbig, 8192 * 2048 / 4);
    cvt_f32_bf16<<<640, 256, 0, stream>>>(W_x, Wx_bf, 160 * 4096 / 4);
    cvt_f32_bf16<<<512, 256, 0, stream>>>(W_dt, Wdt_bf, 4096 * 128 / 4);

    // GEMM1: proj = hidden @ W_in^T  -> split h | gate
    gemm_bt<128, EPI_SPLIT><<<dim3(64, 8, 1), 256, 0, stream>>>(
        (const short*)hid_bf, (const short*)Wbig, h_buf, gate, nullptr,
        1024, 8192, 2048, 8192, 2048);

    conv_silu<<<16384, 256, 0, stream>>>(h_buf, conv_w, conv_b, hc_f, hc_bf);

    // reuse Wbig for W_out (after GEMM1 has consumed W_in)
    cvt_f32_bf16<<<2048, 256, 0, stream>>>(W_out, Wbig, 2048 * 4096 / 4);

    // GEMM2: ssm_p = hc @ W_x^T (N=160), split-K x16, atomic f32 accumulate
    gemm_bt<128, EPI_ATOMIC><<<dim3(2, 8, 16), 256, 0, stream>>>(
        (const short*)hc_bf, (const short*)Wx_bf, ssmp, nullptr, nullptr,
        1024, 160, 4096, 160, 256);

    cvt_ts<<<128, 256, 0, stream>>>(ssmp, ts_bf);

    // GEMM3: dt = softplus(ts @ W_dt^T + b_dt)  (writes into h_buf)
    gemm_bt<128, EPI_SOFTPLUS><<<dim3(32, 8, 1), 256, 0, stream>>>(
        (const short*)ts_bf, (const short*)Wdt_bf, h_buf, nullptr, b_dt,
        1024, 4096, 128, 4096, 128);

    // chunked scan
    scan_p1<<<NCH * 16, 256, 0, stream>>>(h_buf, hc_f, ssmp, A_log, Sbuf, dtsum);
    scan_p2<<<256, 256, 0, stream>>>(A_log, dtsum, Sbuf);
    scan_p3<<<NCH * 16, 256, 0, stream>>>(h_buf, hc_f, ssmp, A_log, D_p, gate, Sbuf, y_bf);

    // GEMM4: out = y @ W_out^T
    gemm_bt<64, EPI_PLAIN><<<dim3(16, 16, 1), 256, 0, stream>>>(
        (const short*)y_bf, (const short*)Wbig, out, nullptr, nullptr,
        1024, 2048, 4096, 2048, 4096);
}

// Round 3
// 252.032 us; speedup vs baseline: 1.9256x; 1.0700x over previous
//
#include <hip/hip_runtime.h>
#include <math.h>

#define AS1 __attribute__((address_space(1)))
#define AS3 __attribute__((address_space(3)))

typedef __attribute__((ext_vector_type(8))) short short8;
typedef __attribute__((ext_vector_type(4))) float f32x4;

#define WAITV(n) asm volatile("s_waitcnt vmcnt(" #n ")" ::: "memory")
#define BARRIER() asm volatile("s_barrier" ::: "memory")

static __device__ __forceinline__ unsigned short f2bf(float f) {
    unsigned u = __float_as_uint(f);
    unsigned r = (u + 0x7fffu + ((u >> 16) & 1u)) >> 16;
    return (unsigned short)r;
}

// ---------------- f32 -> bf16 convert (vectorized x4) ----------------
__global__ __launch_bounds__(256) void cvt_f32_bf16(const float* __restrict__ src,
                                                    unsigned short* __restrict__ dst,
                                                    int n4) {
    int i = blockIdx.x * 256 + threadIdx.x;
    int stride = gridDim.x * 256;
    for (; i < n4; i += stride) {
        float4 v = ((const float4*)src)[i];
        ushort4 o;
        o.x = f2bf(v.x); o.y = f2bf(v.y); o.z = f2bf(v.z); o.w = f2bf(v.w);
        ((ushort4*)dst)[i] = o;
    }
}

// extract ts (cols 0..127 of ssm_p, row stride 160) -> dense bf16 1024x128
__global__ __launch_bounds__(256) void cvt_ts(const float* __restrict__ ssmp,
                                              unsigned short* __restrict__ ts) {
    int i = blockIdx.x * 256 + threadIdx.x;   // < 32768
    int t = i >> 5, c4 = (i & 31) * 4;
    float4 v = *(const float4*)&ssmp[t * 160 + c4];
    ushort4 o;
    o.x = f2bf(v.x); o.y = f2bf(v.y); o.z = f2bf(v.z); o.w = f2bf(v.w);
    *(ushort4*)&ts[t * 128 + c4] = o;
}

// ---------------- depthwise causal conv (K=4) + bias + silu ----------------
__global__ __launch_bounds__(256) void conv_silu(const float* __restrict__ h,
                                                 const float* __restrict__ cw,
                                                 const float* __restrict__ cb,
                                                 float* __restrict__ hc_f,
                                                 unsigned short* __restrict__ hc_bf) {
    int idx = blockIdx.x * 256 + threadIdx.x;   // < 1024*4096
    int d = idx & 4095, t = idx >> 12;
    float acc = cb[d];
    float4 w = *(const float4*)&cw[d * 4];
    const float* wp = (const float*)&w;
#pragma unroll
    for (int k = 0; k < 4; ++k) {
        int tt = t + k - 3;
        if (tt >= 0) acc += h[tt * 4096 + d] * wp[k];
    }
    float s = acc / (1.f + __expf(-acc));   // silu
    hc_f[idx] = s;
    hc_bf[idx] = f2bf(s);
}

// ======== pipelined bf16 MFMA GEMM (GEMM1): C(M,N)=A(M,K)@B(N,K)^T ========
// BM=128, BN=256, BK=64. 512 threads = 8 waves (2M x 4N). 2-buf LDS (96KB),
// counted vmcnt(6), raw s_barrier, XOR-swizzled LDS (pre-swizzled source),
// setprio around MFMA, XCD-bijective block swizzle. EPI: split h|gate.
__global__ __launch_bounds__(512, 2)
void gemm8p_split(const short* __restrict__ A, const short* __restrict__ B,
                  float* __restrict__ C0, float* __restrict__ C1,
                  int M, int N, int K) {
    // buffers: A 128x64 (8192 shorts) + B 256x64 (16384 shorts) = 24576 shorts
    __shared__ short lds[2 * 24576];

    const int tid = threadIdx.x;
    const int wv = tid >> 6, ln = tid & 63;
    const int lr = ln & 15, kg = ln >> 4;
    const int wm = wv >> 2, wn = wv & 3;

    // XCD-bijective swizzle: grid = 256 blocks (8 by x 32 bx), 256 % 8 == 0
    const int bid = blockIdx.x;
    const int swz = (bid & 7) * 32 + (bid >> 3);
    const int by = swz & 7, bx = swz >> 3;
    const int m0 = by * 128;
    const int n0 = bx * 256;
    const int NT = K >> 6;

    f32x4 acc[4][4];
#pragma unroll
    for (int mi = 0; mi < 4; ++mi)
#pragma unroll
        for (int ni = 0; ni < 4; ++ni) acc[mi][ni] = (f32x4){0.f, 0.f, 0.f, 0.f};

    const short* Abase = A + (size_t)m0 * K;
    const short* Bbase = B + (size_t)n0 * K;

    // stage K-tile kt into buffer b. Linear LDS dest (wave-uniform base,
    // lane auto-offset x16B); source col pre-swizzled so that
    // LDS[row*128B + (cb ^ ((row&7)<<4))] = Global[row, cb].
#define STAGE(kt, b)                                                          \
    {                                                                         \
        short* lbase = &lds[(b) * 24576];                                     \
        _Pragma("unroll")                                                     \
        for (int r = 0; r < 2; ++r) {                                         \
            int c = r * 512 + tid;                                            \
            int row = c >> 3, cb8 = (c & 7) << 4;                             \
            int scb = cb8 ^ ((row & 7) << 4);                                 \
            const short* src = Abase + (size_t)row * K + (kt) * 64 + (scb >> 1); \
            short* dst = lbase + (r * 512 + wv * 64) * 8;                     \
            __builtin_amdgcn_global_load_lds((const AS1 void*)src,            \
                                             (AS3 void*)dst, 16, 0, 0);       \
        }                                                                     \
        _Pragma("unroll")                                                     \
        for (int r = 0; r < 4; ++r) {                                         \
            int c = r * 512 + tid;                                            \
            int row = c >> 3, cb8 = (c & 7) << 4;                             \
            int scb = cb8 ^ ((row & 7) << 4);                                 \
            const short* src = Bbase + (size_t)row * K + (kt) * 64 + (scb >> 1); \
            short* dst = lbase + 8192 + (r * 512 + wv * 64) * 8;              \
            __builtin_amdgcn_global_load_lds((const AS1 void*)src,            \
                                             (AS3 void*)dst, 16, 0, 0);       \
        }                                                                     \
    }

    STAGE(0, 0);
    if (NT > 1) STAGE(1, 1);

    for (int kt = 0; kt < NT; ++kt) {
        const int b = kt & 1;
        if (kt + 2 < NT) STAGE(kt + 2, b);   // overwrites buffer read at kt-? no: b = kt&1 is CURRENT buf
        // NOTE: with 2 buffers, tile kt+2 goes into the same buffer as tile kt.
        // The stage above must NOT overwrite buf b before we compute from it!
        // So stage kt+2 AFTER the compute barrier — handled below instead.
        if (kt + 1 < NT) { WAITV(6); } else { WAITV(0); }
        BARRIER();
        // compute tile kt from buffer b
        {
            const short* la = &lds[b * 24576];
            const short* lb = la + 8192;
#pragma unroll
            for (int ks = 0; ks < 2; ++ks) {
                short8 av[4], bv[4];
#pragma unroll
                for (int mi = 0; mi < 4; ++mi) {
                    int row = wm * 64 + mi * 16 + lr;
                    int col = (ks * 32 + kg * 8) ^ ((row & 7) << 3);
                    av[mi] = *(const short8*)&la[row * 64 + col];
                }
#pragma unroll
                for (int ni = 0; ni < 4; ++ni) {
                    int row = wn * 64 + ni * 16 + lr;
                    int col = (ks * 32 + kg * 8) ^ ((row & 7) << 3);
                    bv[ni] = *(const short8*)&lb[row * 64 + col];
                }
                __builtin_amdgcn_s_setprio(1);
#pragma unroll
                for (int mi = 0; mi < 4; ++mi)
#pragma unroll
                    for (int ni = 0; ni < 4; ++ni)
                        acc[mi][ni] = __builtin_amdgcn_mfma_f32_16x16x32_bf16(
                            av[mi], bv[ni], acc[mi][ni], 0, 0, 0);
                __builtin_amdgcn_s_setprio(0);
            }
        }
        BARRIER();
    }
#undef STAGE

    // epilogue: split h | gate (BN=256 tile is uniformly on one side unless
    // it straddles col 4096; handled per element)
#pragma unroll
    for (int mi = 0; mi < 4; ++mi) {
        int crow0 = m0 + wm * 64 + mi * 16 + kg * 4;
#pragma unroll
        for (int ni = 0; ni < 4; ++ni) {
            int ccol = n0 + wn * 64 + ni * 16 + lr;
#pragma unroll
            for (int i = 0; i < 4; ++i) {
                float v = acc[mi][ni][i];
                size_t crow = (size_t)(crow0 + i);
                if (ccol < 4096) C0[crow * 4096 + ccol] = v;
                else C1[crow * 4096 + (ccol - 4096)] = v;
            }
        }
    }
}

// WAIT — the STAGE placement above had a latent bug flagged in the comment:
// with 2 buffers, tile kt+2 shares buffer b with tile kt being computed this
// iteration. Staging it BEFORE the compute would overwrite live data. The
// fix used here: prefetch depth 1 — stage kt+1 (into b^1) at top of iter kt.
// The kernel above is therefore wrong as written... except it never runs:
// the corrected kernel below is the one actually launched.

__global__ __launch_bounds__(512, 2)
void gemm8p_split_v2(const short* __restrict__ A, const short* __restrict__ B,
                     float* __restrict__ C0, float* __restrict__ C1,
                     int M, int N, int K) {
    __shared__ short lds[2 * 24576];

    const int tid = threadIdx.x;
    const int wv = tid >> 6, ln = tid & 63;
    const int lr = ln & 15, kg = ln >> 4;
    const int wm = wv >> 2, wn = wv & 3;

    const int bid = blockIdx.x;
    const int swz = (bid & 7) * 32 + (bid >> 3);
    const int by = swz & 7, bx = swz >> 3;
    const int m0 = by * 128;
    const int n0 = bx * 256;
    const int NT = K >> 6;

    f32x4 acc[4][4];
#pragma unroll
    for (int mi = 0; mi < 4; ++mi)
#pragma unroll
        for (int ni = 0; ni < 4; ++ni) acc[mi][ni] = (f32x4){0.f, 0.f, 0.f, 0.f};

    const short* Abase = A + (size_t)m0 * K;
    const short* Bbase = B + (size_t)n0 * K;

#define STAGE(kt, b)                                                          \
    {                                                                         \
        short* lbase = &lds[(b) * 24576];                                     \
        _Pragma("unroll")                                                     \
        for (int r = 0; r < 2; ++r) {                                         \
            int c = r * 512 + tid;                                            \
            int row = c >> 3, cb8 = (c & 7) << 4;                             \
            int scb = cb8 ^ ((row & 7) << 4);                                 \
            const short* src = Abase + (size_t)row * K + (kt) * 64 + (scb >> 1); \
            short* dst = lbase + (r * 512 + wv * 64) * 8;                     \
            __builtin_amdgcn_global_load_lds((const AS1 void*)src,            \
                                             (AS3 void*)dst, 16, 0, 0);       \
        }                                                                     \
        _Pragma("unroll")                                                     \
        for (int r = 0; r < 4; ++r) {                                         \
            int c = r * 512 + tid;                                            \
            int row = c >> 3, cb8 = (c & 7) << 4;                             \
            int scb = cb8 ^ ((row & 7) << 4);                                 \
            const short* src = Bbase + (size_t)row * K + (kt) * 64 + (scb >> 1); \
            short* dst = lbase + 8192 + (r * 512 + wv * 64) * 8;              \
            __builtin_amdgcn_global_load_lds((const AS1 void*)src,            \
                                             (AS3 void*)dst, 16, 0, 0);       \
        }                                                                     \
    }

    STAGE(0, 0);

    for (int kt = 0; kt < NT; ++kt) {
        const int b = kt & 1;
        // prefetch next tile into the OTHER buffer; its 6 loads stay in
        // flight across this tile's MFMA phase (counted vmcnt, no drain).
        if (kt + 1 < NT) STAGE(kt + 1, b ^ 1);
        if (kt + 1 < NT) { WAITV(6); } else { WAITV(0); }
        BARRIER();   // buf b ready for all waves; all waves done reading b^1
        {
            const short* la = &lds[b * 24576];
            const short* lb = la + 8192;
#pragma unroll
            for (int ks = 0; ks < 2; ++ks) {
                short8 av[4], bv[4];
#pragma unroll
                for (int mi = 0; mi < 4; ++mi) {
                    int row = wm * 64 + mi * 16 + lr;
                    int col = (ks * 32 + kg * 8) ^ ((row & 7) << 3);
                    av[mi] = *(const short8*)&la[row * 64 + col];
                }
#pragma unroll
                for (int ni = 0; ni < 4; ++ni) {
                    int row = wn * 64 + ni * 16 + lr;
                    int col = (ks * 32 + kg * 8) ^ ((row & 7) << 3);
                    bv[ni] = *(const short8*)&lb[row * 64 + col];
                }
                __builtin_amdgcn_s_setprio(1);
#pragma unroll
                for (int mi = 0; mi < 4; ++mi)
#pragma unroll
                    for (int ni = 0; ni < 4; ++ni)
                        acc[mi][ni] = __builtin_amdgcn_mfma_f32_16x16x32_bf16(
                            av[mi], bv[ni], acc[mi][ni], 0, 0, 0);
                __builtin_amdgcn_s_setprio(0);
            }
        }
        BARRIER();   // all waves done reading buf b before next iter stages into... b^1? no:
        // next iter stages into (b^1)^1 = b — which this iter just finished reading. Correct.
    }
#undef STAGE

#pragma unroll
    for (int mi = 0; mi < 4; ++mi) {
        int crow0 = m0 + wm * 64 + mi * 16 + kg * 4;
#pragma unroll
        for (int ni = 0; ni < 4; ++ni) {
            int ccol = n0 + wn * 64 + ni * 16 + lr;
#pragma unroll
            for (int i = 0; i < 4; ++i) {
                float v = acc[mi][ni][i];
                size_t crow = (size_t)(crow0 + i);
                if (ccol < 4096) C0[crow * 4096 + ccol] = v;
                else C1[crow * 4096 + (ccol - 4096)] = v;
            }
        }
    }
}

// ---------------- 2-phase bf16 MFMA GEMM (GEMM2/3/4) ----------------
enum { EPI_PLAIN = 0, EPI_SPLIT = 1, EPI_ATOMIC = 2, EPI_SOFTPLUS = 3 };

template <int BM, int EPI>
__global__ __launch_bounds__(256)
void gemm_bt(const short* __restrict__ A, const short* __restrict__ B,
             float* __restrict__ C, float* __restrict__ C2,
             const float* __restrict__ bias,
             int M, int N, int K, int ldc, int kcLen) {
    __shared__ short A_lds[BM * 32];
    __shared__ short B_lds[128 * 32];
    const int tid = threadIdx.x;
    const int wv = tid >> 6, ln = tid & 63;
    const int lr = ln & 15, kg = ln >> 4;
    const int m0 = blockIdx.y * BM;
    const int n0 = blockIdx.x * 128;
    const int kbeg = blockIdx.z * kcLen;
    const int kend = kbeg + kcLen;
    const int wm = wv >> 1, wn = wv & 1;
    constexpr int MR = BM / 32;

    f32x4 acc[MR][4];
#pragma unroll
    for (int mi = 0; mi < MR; ++mi)
#pragma unroll
        for (int ni = 0; ni < 4; ++ni) acc[mi][ni] = (f32x4){0.f, 0.f, 0.f, 0.f};

    const int arow = tid >> 2;
    const int kq8 = (tid & 3) * 8;

    for (int k0 = kbeg; k0 < kend; k0 += 32) {
#pragma unroll
        for (int r = 0; r < BM / 64; ++r) {
            const short* srcA = A + (size_t)(m0 + r * 64 + arow) * K + (k0 + kq8);
            short* dstA = &A_lds[(r * 64 + wv * 16) * 32];
            __builtin_amdgcn_global_load_lds((const AS1 void*)srcA, (AS3 void*)dstA, 16, 0, 0);
        }
#pragma unroll
        for (int r = 0; r < 2; ++r) {
            int brow = n0 + r * 64 + arow;
            if (brow > N - 1) brow = N - 1;
            const short* srcB = B + (size_t)brow * K + (k0 + kq8);
            short* dstB = &B_lds[(r * 64 + wv * 16) * 32];
            __builtin_amdgcn_global_load_lds((const AS1 void*)srcB, (AS3 void*)dstB, 16, 0, 0);
        }
        __syncthreads();

        short8 av[MR], bv[4];
#pragma unroll
        for (int mi = 0; mi < MR; ++mi)
            av[mi] = *(const short8*)&A_lds[(wm * (BM / 2) + mi * 16 + lr) * 32 + kg * 8];
#pragma unroll
        for (int ni = 0; ni < 4; ++ni)
            bv[ni] = *(const short8*)&B_lds[(wn * 64 + ni * 16 + lr) * 32 + kg * 8];
#pragma unroll
        for (int mi = 0; mi < MR; ++mi)
#pragma unroll
            for (int ni = 0; ni < 4; ++ni)
                acc[mi][ni] = __builtin_amdgcn_mfma_f32_16x16x32_bf16(av[mi], bv[ni], acc[mi][ni], 0, 0, 0);
        __syncthreads();
    }

#pragma unroll
    for (int mi = 0; mi < MR; ++mi) {
        int crow0 = m0 + wm * (BM / 2) + mi * 16 + kg * 4;
#pragma unroll
        for (int ni = 0; ni < 4; ++ni) {
            int ccol = n0 + wn * 64 + ni * 16 + lr;
#pragma unroll
            for (int i = 0; i < 4; ++i) {
                float v = acc[mi][ni][i];
                size_t crow = (size_t)(crow0 + i);
                if constexpr (EPI == EPI_PLAIN) {
                    C[crow * ldc + ccol] = v;
                } else if constexpr (EPI == EPI_SPLIT) {
                    if (ccol < 4096) C[crow * 4096 + ccol] = v;
                    else C2[crow * 4096 + (ccol - 4096)] = v;
                } else if constexpr (EPI == EPI_ATOMIC) {
                    if (ccol < N) atomicAdd(&C[crow * ldc + ccol], v);
                } else {
                    float x = v + bias[ccol];
                    C[crow * ldc + ccol] = fmaxf(x, 0.f) + log1pf(__expf(-fabsf(x)));
                }
            }
        }
    }
}

// ================= chunked selective scan =================
#define CLEN 16
#define NCH 64

__global__ __launch_bounds__(256)
void scan_p1(const float* __restrict__ dt, const float* __restrict__ hc,
             const float* __restrict__ ssmp, const float* __restrict__ A_log,
             float* __restrict__ Sbuf, float* __restrict__ dtsum) {
    const int tid = threadIdx.x;
    const int c = blockIdx.x & (NCH - 1);
    const int db = blockIdx.x >> 6;
    const int d = db * 256 + tid;
    const int t0 = c * CLEN;

    float Ac[16];
#pragma unroll
    for (int i = 0; i < 4; ++i) {
        float4 v = *(const float4*)&A_log[d * 16 + i * 4];
        Ac[i*4+0] = -__expf(v.x); Ac[i*4+1] = -__expf(v.y);
        Ac[i*4+2] = -__expf(v.z); Ac[i*4+3] = -__expf(v.w);
    }

    __shared__ float sB[CLEN][16];
    sB[tid >> 4][tid & 15] = ssmp[(t0 + (tid >> 4)) * 160 + 128 + (tid & 15)];
    __syncthreads();

    float st[16];
#pragma unroll
    for (int n = 0; n < 16; ++n) st[n] = 0.f;
    float ds = 0.f;

    for (int tt = 0; tt < CLEN; ++tt) {
        float dtv = dt[(size_t)(t0 + tt) * 4096 + d];
        float hcv = hc[(size_t)(t0 + tt) * 4096 + d];
        float du = dtv * hcv;
        ds += dtv;
#pragma unroll
        for (int n = 0; n < 16; ++n) {
            float dA = __expf(dtv * Ac[n]);
            st[n] = fmaf(dA, st[n], du * sB[tt][n]);
        }
    }

    float* o = Sbuf + ((size_t)c * 4096 + d) * 16;
#pragma unroll
    for (int i = 0; i < 4; ++i)
        *(float4*)&o[i * 4] = make_float4(st[i*4], st[i*4+1], st[i*4+2], st[i*4+3]);
    dtsum[c * 4096 + d] = ds;
}

__global__ __launch_bounds__(256)
void scan_p2(const float* __restrict__ A_log, const float* __restrict__ dtsum,
             float* __restrict__ S) {
    const int idx = blockIdx.x * 256 + threadIdx.x;
    const int d = idx >> 4;
    const float Ac = -__expf(A_log[idx]);
    float s = 0.f;
    for (int c = 0; c < NCH; ++c) {
        size_t o = (size_t)c * 65536 + idx;
        float sl = S[o];
        float P = __expf(Ac * dtsum[c * 4096 + d]);
        S[o] = s;
        s = fmaf(P, s, sl);
    }
}

__global__ __launch_bounds__(256)
void scan_p3(const float* __restrict__ dt, const float* __restrict__ hc,
             const float* __restrict__ ssmp, const float* __restrict__ A_log,
             const float* __restrict__ Dp, const float* __restrict__ gate,
             const float* __restrict__ Sinit, unsigned short* __restrict__ y_bf) {
    const int tid = threadIdx.x;
    const int c = blockIdx.x & (NCH - 1);
    const int db = blockIdx.x >> 6;
    const int d = db * 256 + tid;
    const int t0 = c * CLEN;

    float Ac[16];
#pragma unroll
    for (int i = 0; i < 4; ++i) {
        float4 v = *(const float4*)&A_log[d * 16 + i * 4];
        Ac[i*4+0] = -__expf(v.x); Ac[i*4+1] = -__expf(v.y);
        Ac[i*4+2] = -__expf(v.z); Ac[i*4+3] = -__expf(v.w);
    }
    const float Dcoef = Dp[d];

    __shared__ float sB[CLEN][16], sC[CLEN][16];
    {
        int tt = tid >> 4, nn = tid & 15;
        sB[tt][nn] = ssmp[(t0 + tt) * 160 + 128 + nn];
        sC[tt][nn] = ssmp[(t0 + tt) * 160 + 144 + nn];
    }
    __syncthreads();

    float st[16];
    {
        const float* si = Sinit + ((size_t)c * 4096 + d) * 16;
#pragma unroll
        for (int i = 0; i < 4; ++i) {
            float4 v = *(const float4*)&si[i * 4];
            st[i*4] = v.x; st[i*4+1] = v.y; st[i*4+2] = v.z; st[i*4+3] = v.w;
        }
    }

    for (int tt = 0; tt < CLEN; ++tt) {
        size_t g = (size_t)(t0 + tt) * 4096 + d;
        float dtv = dt[g];
        float hcv = hc[g];
        float du = dtv * hcv;
        float p[16];
#pragma unroll
        for (int n = 0; n < 16; ++n) {
            float dA = __expf(dtv * Ac[n]);
            st[n] = fmaf(dA, st[n], du * sB[tt][n]);
            p[n] = st[n] * sC[tt][n];
        }
#pragma unroll
        for (int n = 0; n < 8; ++n) p[n] += p[n + 8];
#pragma unroll
        for (int n = 0; n < 4; ++n) p[n] += p[n + 4];
        p[0] += p[2]; p[1] += p[3];
        float csum = p[0] + p[1];
        float gv = gate[g];
        float yv = (csum + hcv * Dcoef) * (gv / (1.f + __expf(-gv)));
        y_bf[g] = f2bf(yv);
    }
}

// ---------------- launch ----------------
extern "C" void kernel_launch(void* const* d_in, const int* in_sizes, int n_in,
                              void* d_out, int out_size, void* d_ws, size_t ws_size,
                              hipStream_t stream) {
    (void)in_sizes; (void)n_in; (void)out_size; (void)ws_size;
    const float* hidden = (const float*)d_in[0];
    const float* W_in   = (const float*)d_in[1];
    const float* conv_w = (const float*)d_in[2];
    const float* conv_b = (const float*)d_in[3];
    const float* W_x    = (const float*)d_in[4];
    const float* W_dt   = (const float*)d_in[5];
    const float* b_dt   = (const float*)d_in[6];
    const float* A_log  = (const float*)d_in[7];
    const float* D_p    = (const float*)d_in[8];
    const float* W_out  = (const float*)d_in[9];
    float* out = (float*)d_out;

    char* w = (char*)d_ws;
    unsigned short* hid_bf = (unsigned short*)w;  w += (size_t)1024 * 2048 * 2;
    unsigned short* Wbig   = (unsigned short*)w;  w += (size_t)8192 * 2048 * 2;
    float* h_buf           = (float*)w;           w += (size_t)1024 * 4096 * 4;
    float* gate            = (float*)w;           w += (size_t)1024 * 4096 * 4;
    float* hc_f            = (float*)w;           w += (size_t)1024 * 4096 * 4;
    unsigned short* hc_bf  = (unsigned short*)w;  w += (size_t)1024 * 4096 * 2;
    float* ssmp            = (float*)w;           w += (size_t)1024 * 160 * 4;
    unsigned short* ts_bf  = (unsigned short*)w;  w += (size_t)1024 * 128 * 2;
    unsigned short* Wx_bf  = (unsigned short*)w;  w += (size_t)160 * 4096 * 2;
    unsigned short* Wdt_bf = (unsigned short*)w;  w += (size_t)4096 * 128 * 2;
    unsigned short* y_bf   = (unsigned short*)w;  w += (size_t)1024 * 4096 * 2;
    float* Sbuf            = (float*)w;           w += (size_t)NCH * 4096 * 16 * 4;
    float* dtsum           = (float*)w;           w += (size_t)NCH * 4096 * 4;

    hipMemsetAsync(ssmp, 0, (size_t)1024 * 160 * 4, stream);

    cvt_f32_bf16<<<2048, 256, 0, stream>>>(hidden, hid_bf, 1024 * 2048 / 4);
    cvt_f32_bf16<<<4096, 256, 0, stream>>>(W_in, Wbig, 8192 * 2048 / 4);
    cvt_f32_bf16<<<640, 256, 0, stream>>>(W_x, Wx_bf, 160 * 4096 / 4);
    cvt_f32_bf16<<<512, 256, 0, stream>>>(W_dt, Wdt_bf, 4096 * 128 / 4);

    // GEMM1: proj = hidden @ W_in^T -> split h | gate (pipelined kernel)
    gemm8p_split_v2<<<256, 512, 0, stream>>>(
        (const short*)hid_bf, (const short*)Wbig, h_buf, gate, 1024, 8192, 2048);

    conv_silu<<<16384, 256, 0, stream>>>(h_buf, conv_w, conv_b, hc_f, hc_bf);

    cvt_f32_bf16<<<2048, 256, 0, stream>>>(W_out, Wbig, 2048 * 4096 / 4);

    gemm_bt<128, EPI_ATOMIC><<<dim3(2, 8, 16), 256, 0, stream>>>(
        (const short*)hc_bf, (const short*)Wx_bf, ssmp, nullptr, nullptr,
        1024, 160, 4096, 160, 256);

    cvt_ts<<<128, 256, 0, stream>>>(ssmp, ts_bf);

    gemm_bt<128, EPI_SOFTPLUS><<<dim3(32, 8, 1), 256, 0, stream>>>(
        (const short*)ts_bf, (const short*)Wdt_bf, h_buf, nullptr, b_dt,
        1024, 4096, 128, 4096, 128);

    scan_p1<<<NCH * 16, 256, 0, stream>>>(h_buf, hc_f, ssmp, A_log, Sbuf, dtsum);
    scan_p2<<<256, 256, 0, stream>>>(A_log, dtsum, Sbuf);
    scan_p3<<<NCH * 16, 256, 0, stream>>>(h_buf, hc_f, ssmp, A_log, D_p, gate, Sbuf, y_bf);

    gemm_bt<64, EPI_PLAIN><<<dim3(16, 16, 1), 256, 0, stream>>>(
        (const short*)y_bf, (const short*)Wbig, out, nullptr, nullptr,
        1024, 2048, 4096, 2048, 4096);
}

// Round 4
// 236.299 us; speedup vs baseline: 2.0538x; 1.0666x over previous
//
#include <hip/hip_runtime.h>
#include <math.h>

#define AS1 __attribute__((address_space(1)))
#define AS3 __attribute__((address_space(3)))

typedef __attribute__((ext_vector_type(8))) short short8;
typedef __attribute__((ext_vector_type(4))) float f32x4;

#define WAITV(n) asm volatile("s_waitcnt vmcnt(" #n ")" ::: "memory")
#define BARRIER() asm volatile("s_barrier" ::: "memory")

static __device__ __forceinline__ unsigned short f2bf(float f) {
    unsigned u = __float_as_uint(f);
    unsigned r = (u + 0x7fffu + ((u >> 16) & 1u)) >> 16;
    return (unsigned short)r;
}

// ---------------- f32 -> bf16 convert (vectorized x4) ----------------
__global__ __launch_bounds__(256) void cvt_f32_bf16(const float* __restrict__ src,
                                                    unsigned short* __restrict__ dst,
                                                    int n4) {
    int i = blockIdx.x * 256 + threadIdx.x;
    int stride = gridDim.x * 256;
    for (; i < n4; i += stride) {
        float4 v = ((const float4*)src)[i];
        ushort4 o;
        o.x = f2bf(v.x); o.y = f2bf(v.y); o.z = f2bf(v.z); o.w = f2bf(v.w);
        ((ushort4*)dst)[i] = o;
    }
}

// extract ts (cols 0..127 of ssm_p, row stride 160) -> dense bf16 1024x128
__global__ __launch_bounds__(256) void cvt_ts(const float* __restrict__ ssmp,
                                              unsigned short* __restrict__ ts) {
    int i = blockIdx.x * 256 + threadIdx.x;   // < 32768
    int t = i >> 5, c4 = (i & 31) * 4;
    float4 v = *(const float4*)&ssmp[t * 160 + c4];
    ushort4 o;
    o.x = f2bf(v.x); o.y = f2bf(v.y); o.z = f2bf(v.z); o.w = f2bf(v.w);
    *(ushort4*)&ts[t * 128 + c4] = o;
}

// ---------------- depthwise causal conv (K=4) + bias + silu ----------------
__global__ __launch_bounds__(256) void conv_silu(const float* __restrict__ h,
                                                 const float* __restrict__ cw,
                                                 const float* __restrict__ cb,
                                                 float* __restrict__ hc_f,
                                                 unsigned short* __restrict__ hc_bf) {
    int idx = blockIdx.x * 256 + threadIdx.x;   // < 1024*4096
    int d = idx & 4095, t = idx >> 12;
    float acc = cb[d];
    float4 w = *(const float4*)&cw[d * 4];
    const float* wp = (const float*)&w;
#pragma unroll
    for (int k = 0; k < 4; ++k) {
        int tt = t + k - 3;
        if (tt >= 0) acc += h[tt * 4096 + d] * wp[k];
    }
    float s = acc / (1.f + __expf(-acc));   // silu
    hc_f[idx] = s;
    hc_bf[idx] = f2bf(s);
}

// ======== pipelined bf16 MFMA GEMM: C(M,N) = A(M,K) @ B(N,K)^T ========
// BM=128, BN=256, BK=64. 512 threads = 8 waves (2M x 4N). Double-buffered
// 96KB LDS, counted vmcnt(6) (loads stay in flight across barriers), raw
// s_barrier, XOR-swizzled LDS via pre-swizzled global source (linear LDS
// dest for global_load_lds), setprio around MFMA, XCD-bijective swizzle.
// M is fixed at 1024 (by = 8 rows of 128). kchunk = K per z-block.
enum { P_SPLIT = 0, P_ATOMIC = 1 };

template <int EPI>
__global__ __launch_bounds__(512, 2)
void gemm8p(const short* __restrict__ A, const short* __restrict__ B,
            float* __restrict__ C0, float* __restrict__ C1,
            int N, int K, int kchunk) {
    __shared__ short lds[2 * 24576];   // per buf: A 128x64 (8192) + B 256x64 (16384)

    const int tid = threadIdx.x;
    const int wv = tid >> 6, ln = tid & 63;
    const int lr = ln & 15, kg = ln >> 4;
    const int wm = wv >> 2, wn = wv & 3;

    // XCD-bijective block swizzle (gridDim.x % 8 == 0): XCD j gets a
    // contiguous swz chunk -> B-panel locality per XCD.
    const int nwg = gridDim.x;
    const int bid = blockIdx.x;
    const int swz = (bid & 7) * (nwg >> 3) + (bid >> 3);
    const int by = swz & 7, bx = swz >> 3;
    const int m0 = by * 128;
    const int n0 = bx * 256;
    const int kbeg = blockIdx.z * kchunk;
    const int NT = kchunk >> 6;

    f32x4 acc[4][4];
#pragma unroll
    for (int mi = 0; mi < 4; ++mi)
#pragma unroll
        for (int ni = 0; ni < 4; ++ni) acc[mi][ni] = (f32x4){0.f, 0.f, 0.f, 0.f};

    const short* Abase = A + (size_t)m0 * K + kbeg;
    const short* Bbase = B + (size_t)n0 * K + kbeg;

    // Stage K-tile kt into buffer b. LDS dest is linear (wave-uniform base +
    // lane*16B); the source column is pre-swizzled so that after the linear
    // write, LDS[row][col^((row&7)<<3 shorts)] = Global[row][col]  (rule 21).
#define STAGE(kt, b)                                                          \
    {                                                                         \
        short* lbase = &lds[(b) * 24576];                                     \
        _Pragma("unroll")                                                     \
        for (int r = 0; r < 2; ++r) {                                         \
            int c = r * 512 + tid;                                            \
            int row = c >> 3, cb8 = (c & 7) << 4;                             \
            int scb = cb8 ^ ((row & 7) << 4);                                 \
            const short* src = Abase + (size_t)row * K + (kt) * 64 + (scb >> 1); \
            short* dst = lbase + (r * 512 + wv * 64) * 8;                     \
            __builtin_amdgcn_global_load_lds((const AS1 void*)src,            \
                                             (AS3 void*)dst, 16, 0, 0);       \
        }                                                                     \
        _Pragma("unroll")                                                     \
        for (int r = 0; r < 4; ++r) {                                         \
            int c = r * 512 + tid;                                            \
            int row = c >> 3, cb8 = (c & 7) << 4;                             \
            int scb = cb8 ^ ((row & 7) << 4);                                 \
            const short* src = Bbase + (size_t)row * K + (kt) * 64 + (scb >> 1); \
            short* dst = lbase + 8192 + (r * 512 + wv * 64) * 8;              \
            __builtin_amdgcn_global_load_lds((const AS1 void*)src,            \
                                             (AS3 void*)dst, 16, 0, 0);       \
        }                                                                     \
    }

    STAGE(0, 0);

    for (int kt = 0; kt < NT; ++kt) {
        const int b = kt & 1;
        // prefetch next tile into the other buffer; its 6 loads stay in
        // flight across this tile's MFMA phase (counted vmcnt, no drain).
        if (kt + 1 < NT) STAGE(kt + 1, b ^ 1);
        if (kt + 1 < NT) { WAITV(6); } else { WAITV(0); }
        BARRIER();   // buf b ready; all waves done reading b^1
        {
            const short* la = &lds[b * 24576];
            const short* lb = la + 8192;
#pragma unroll
            for (int ks = 0; ks < 2; ++ks) {
                short8 av[4], bv[4];
#pragma unroll
                for (int mi = 0; mi < 4; ++mi) {
                    int row = wm * 64 + mi * 16 + lr;
                    int col = (ks * 32 + kg * 8) ^ ((row & 7) << 3);
                    av[mi] = *(const short8*)&la[row * 64 + col];
                }
#pragma unroll
                for (int ni = 0; ni < 4; ++ni) {
                    int row = wn * 64 + ni * 16 + lr;
                    int col = (ks * 32 + kg * 8) ^ ((row & 7) << 3);
                    bv[ni] = *(const short8*)&lb[row * 64 + col];
                }
                __builtin_amdgcn_s_setprio(1);
#pragma unroll
                for (int mi = 0; mi < 4; ++mi)
#pragma unroll
                    for (int ni = 0; ni < 4; ++ni)
                        acc[mi][ni] = __builtin_amdgcn_mfma_f32_16x16x32_bf16(
                            av[mi], bv[ni], acc[mi][ni], 0, 0, 0);
                __builtin_amdgcn_s_setprio(0);
            }
        }
        BARRIER();   // all waves done with buf b before it is re-staged next iter
    }
#undef STAGE

#pragma unroll
    for (int mi = 0; mi < 4; ++mi) {
        int crow0 = m0 + wm * 64 + mi * 16 + kg * 4;
#pragma unroll
        for (int ni = 0; ni < 4; ++ni) {
            int ccol = n0 + wn * 64 + ni * 16 + lr;
#pragma unroll
            for (int i = 0; i < 4; ++i) {
                float v = acc[mi][ni][i];
                size_t crow = (size_t)(crow0 + i);
                if constexpr (EPI == P_SPLIT) {
                    if (ccol < 4096) C0[crow * 4096 + ccol] = v;
                    else C1[crow * 4096 + (ccol - 4096)] = v;
                } else {   // split-K partial: accumulate into zeroed C0
                    atomicAdd(&C0[crow * N + ccol], v);
                }
            }
        }
    }
}

// ---------------- 2-phase bf16 MFMA GEMM (GEMM2/3) ----------------
enum { EPI_PLAIN = 0, EPI_SPLIT = 1, EPI_ATOMIC = 2, EPI_SOFTPLUS = 3 };

template <int BM, int EPI>
__global__ __launch_bounds__(256)
void gemm_bt(const short* __restrict__ A, const short* __restrict__ B,
             float* __restrict__ C, float* __restrict__ C2,
             const float* __restrict__ bias,
             int M, int N, int K, int ldc, int kcLen) {
    __shared__ short A_lds[BM * 32];
    __shared__ short B_lds[128 * 32];
    const int tid = threadIdx.x;
    const int wv = tid >> 6, ln = tid & 63;
    const int lr = ln & 15, kg = ln >> 4;
    const int m0 = blockIdx.y * BM;
    const int n0 = blockIdx.x * 128;
    const int kbeg = blockIdx.z * kcLen;
    const int kend = kbeg + kcLen;
    const int wm = wv >> 1, wn = wv & 1;
    constexpr int MR = BM / 32;

    f32x4 acc[MR][4];
#pragma unroll
    for (int mi = 0; mi < MR; ++mi)
#pragma unroll
        for (int ni = 0; ni < 4; ++ni) acc[mi][ni] = (f32x4){0.f, 0.f, 0.f, 0.f};

    const int arow = tid >> 2;
    const int kq8 = (tid & 3) * 8;

    for (int k0 = kbeg; k0 < kend; k0 += 32) {
#pragma unroll
        for (int r = 0; r < BM / 64; ++r) {
            const short* srcA = A + (size_t)(m0 + r * 64 + arow) * K + (k0 + kq8);
            short* dstA = &A_lds[(r * 64 + wv * 16) * 32];
            __builtin_amdgcn_global_load_lds((const AS1 void*)srcA, (AS3 void*)dstA, 16, 0, 0);
        }
#pragma unroll
        for (int r = 0; r < 2; ++r) {
            int brow = n0 + r * 64 + arow;
            if (brow > N - 1) brow = N - 1;
            const short* srcB = B + (size_t)brow * K + (k0 + kq8);
            short* dstB = &B_lds[(r * 64 + wv * 16) * 32];
            __builtin_amdgcn_global_load_lds((const AS1 void*)srcB, (AS3 void*)dstB, 16, 0, 0);
        }
        __syncthreads();

        short8 av[MR], bv[4];
#pragma unroll
        for (int mi = 0; mi < MR; ++mi)
            av[mi] = *(const short8*)&A_lds[(wm * (BM / 2) + mi * 16 + lr) * 32 + kg * 8];
#pragma unroll
        for (int ni = 0; ni < 4; ++ni)
            bv[ni] = *(const short8*)&B_lds[(wn * 64 + ni * 16 + lr) * 32 + kg * 8];
#pragma unroll
        for (int mi = 0; mi < MR; ++mi)
#pragma unroll
            for (int ni = 0; ni < 4; ++ni)
                acc[mi][ni] = __builtin_amdgcn_mfma_f32_16x16x32_bf16(av[mi], bv[ni], acc[mi][ni], 0, 0, 0);
        __syncthreads();
    }

#pragma unroll
    for (int mi = 0; mi < MR; ++mi) {
        int crow0 = m0 + wm * (BM / 2) + mi * 16 + kg * 4;
#pragma unroll
        for (int ni = 0; ni < 4; ++ni) {
            int ccol = n0 + wn * 64 + ni * 16 + lr;
#pragma unroll
            for (int i = 0; i < 4; ++i) {
                float v = acc[mi][ni][i];
                size_t crow = (size_t)(crow0 + i);
                if constexpr (EPI == EPI_PLAIN) {
                    C[crow * ldc + ccol] = v;
                } else if constexpr (EPI == EPI_SPLIT) {
                    if (ccol < 4096) C[crow * 4096 + ccol] = v;
                    else C2[crow * 4096 + (ccol - 4096)] = v;
                } else if constexpr (EPI == EPI_ATOMIC) {
                    if (ccol < N) atomicAdd(&C[crow * ldc + ccol], v);
                } else {
                    float x = v + bias[ccol];
                    C[crow * ldc + ccol] = fmaxf(x, 0.f) + log1pf(__expf(-fabsf(x)));
                }
            }
        }
    }
}

// ================= chunked selective scan =================
#define CLEN 16
#define NCH 64

__global__ __launch_bounds__(256)
void scan_p1(const float* __restrict__ dt, const float* __restrict__ hc,
             const float* __restrict__ ssmp, const float* __restrict__ A_log,
             float* __restrict__ Sbuf, float* __restrict__ dtsum) {
    const int tid = threadIdx.x;
    const int c = blockIdx.x & (NCH - 1);
    const int db = blockIdx.x >> 6;
    const int d = db * 256 + tid;
    const int t0 = c * CLEN;

    float Ac[16];
#pragma unroll
    for (int i = 0; i < 4; ++i) {
        float4 v = *(const float4*)&A_log[d * 16 + i * 4];
        Ac[i*4+0] = -__expf(v.x); Ac[i*4+1] = -__expf(v.y);
        Ac[i*4+2] = -__expf(v.z); Ac[i*4+3] = -__expf(v.w);
    }

    __shared__ float sB[CLEN][16];
    sB[tid >> 4][tid & 15] = ssmp[(t0 + (tid >> 4)) * 160 + 128 + (tid & 15)];
    __syncthreads();

    float st[16];
#pragma unroll
    for (int n = 0; n < 16; ++n) st[n] = 0.f;
    float ds = 0.f;

    for (int tt = 0; tt < CLEN; ++tt) {
        float dtv = dt[(size_t)(t0 + tt) * 4096 + d];
        float hcv = hc[(size_t)(t0 + tt) * 4096 + d];
        float du = dtv * hcv;
        ds += dtv;
#pragma unroll
        for (int n = 0; n < 16; ++n) {
            float dA = __expf(dtv * Ac[n]);
            st[n] = fmaf(dA, st[n], du * sB[tt][n]);
        }
    }

    float* o = Sbuf + ((size_t)c * 4096 + d) * 16;
#pragma unroll
    for (int i = 0; i < 4; ++i)
        *(float4*)&o[i * 4] = make_float4(st[i*4], st[i*4+1], st[i*4+2], st[i*4+3]);
    dtsum[c * 4096 + d] = ds;
}

__global__ __launch_bounds__(256)
void scan_p2(const float* __restrict__ A_log, const float* __restrict__ dtsum,
             float* __restrict__ S) {
    const int idx = blockIdx.x * 256 + threadIdx.x;
    const int d = idx >> 4;
    const float Ac = -__expf(A_log[idx]);
    float s = 0.f;
    for (int c = 0; c < NCH; ++c) {
        size_t o = (size_t)c * 65536 + idx;
        float sl = S[o];
        float P = __expf(Ac * dtsum[c * 4096 + d]);
        S[o] = s;
        s = fmaf(P, s, sl);
    }
}

__global__ __launch_bounds__(256)
void scan_p3(const float* __restrict__ dt, const float* __restrict__ hc,
             const float* __restrict__ ssmp, const float* __restrict__ A_log,
             const float* __restrict__ Dp, const float* __restrict__ gate,
             const float* __restrict__ Sinit, unsigned short* __restrict__ y_bf) {
    const int tid = threadIdx.x;
    const int c = blockIdx.x & (NCH - 1);
    const int db = blockIdx.x >> 6;
    const int d = db * 256 + tid;
    const int t0 = c * CLEN;

    float Ac[16];
#pragma unroll
    for (int i = 0; i < 4; ++i) {
        float4 v = *(const float4*)&A_log[d * 16 + i * 4];
        Ac[i*4+0] = -__expf(v.x); Ac[i*4+1] = -__expf(v.y);
        Ac[i*4+2] = -__expf(v.z); Ac[i*4+3] = -__expf(v.w);
    }
    const float Dcoef = Dp[d];

    __shared__ float sB[CLEN][16], sC[CLEN][16];
    {
        int tt = tid >> 4, nn = tid & 15;
        sB[tt][nn] = ssmp[(t0 + tt) * 160 + 128 + nn];
        sC[tt][nn] = ssmp[(t0 + tt) * 160 + 144 + nn];
    }
    __syncthreads();

    float st[16];
    {
        const float* si = Sinit + ((size_t)c * 4096 + d) * 16;
#pragma unroll
        for (int i = 0; i < 4; ++i) {
            float4 v = *(const float4*)&si[i * 4];
            st[i*4] = v.x; st[i*4+1] = v.y; st[i*4+2] = v.z; st[i*4+3] = v.w;
        }
    }

    for (int tt = 0; tt < CLEN; ++tt) {
        size_t g = (size_t)(t0 + tt) * 4096 + d;
        float dtv = dt[g];
        float hcv = hc[g];
        float du = dtv * hcv;
        float p[16];
#pragma unroll
        for (int n = 0; n < 16; ++n) {
            float dA = __expf(dtv * Ac[n]);
            st[n] = fmaf(dA, st[n], du * sB[tt][n]);
            p[n] = st[n] * sC[tt][n];
        }
#pragma unroll
        for (int n = 0; n < 8; ++n) p[n] += p[n + 8];
#pragma unroll
        for (int n = 0; n < 4; ++n) p[n] += p[n + 4];
        p[0] += p[2]; p[1] += p[3];
        float csum = p[0] + p[1];
        float gv = gate[g];
        float yv = (csum + hcv * Dcoef) * (gv / (1.f + __expf(-gv)));
        y_bf[g] = f2bf(yv);
    }
}

// ---------------- launch ----------------
extern "C" void kernel_launch(void* const* d_in, const int* in_sizes, int n_in,
                              void* d_out, int out_size, void* d_ws, size_t ws_size,
                              hipStream_t stream) {
    (void)in_sizes; (void)n_in; (void)out_size; (void)ws_size;
    const float* hidden = (const float*)d_in[0];
    const float* W_in   = (const float*)d_in[1];
    const float* conv_w = (const float*)d_in[2];
    const float* conv_b = (const float*)d_in[3];
    const float* W_x    = (const float*)d_in[4];
    const float* W_dt   = (const float*)d_in[5];
    const float* b_dt   = (const float*)d_in[6];
    const float* A_log  = (const float*)d_in[7];
    const float* D_p    = (const float*)d_in[8];
    const float* W_out  = (const float*)d_in[9];
    float* out = (float*)d_out;

    char* w = (char*)d_ws;
    unsigned short* hid_bf = (unsigned short*)w;  w += (size_t)1024 * 2048 * 2;
    unsigned short* Wbig   = (unsigned short*)w;  w += (size_t)8192 * 2048 * 2;
    float* h_buf           = (float*)w;           w += (size_t)1024 * 4096 * 4;
    float* gate            = (float*)w;           w += (size_t)1024 * 4096 * 4;
    float* hc_f            = (float*)w;           w += (size_t)1024 * 4096 * 4;
    unsigned short* hc_bf  = (unsigned short*)w;  w += (size_t)1024 * 4096 * 2;
    float* ssmp            = (float*)w;           w += (size_t)1024 * 160 * 4;
    unsigned short* ts_bf  = (unsigned short*)w;  w += (size_t)1024 * 128 * 2;
    unsigned short* Wx_bf  = (unsigned short*)w;  w += (size_t)160 * 4096 * 2;
    unsigned short* Wdt_bf = (unsigned short*)w;  w += (size_t)4096 * 128 * 2;
    unsigned short* y_bf   = (unsigned short*)w;  w += (size_t)1024 * 4096 * 2;
    float* Sbuf            = (float*)w;           w += (size_t)NCH * 4096 * 16 * 4;
    float* dtsum           = (float*)w;           w += (size_t)NCH * 4096 * 4;

    hipMemsetAsync(ssmp, 0, (size_t)1024 * 160 * 4, stream);
    hipMemsetAsync(out, 0, (size_t)1024 * 2048 * 4, stream);   // split-K atomic target

    cvt_f32_bf16<<<2048, 256, 0, stream>>>(hidden, hid_bf, 1024 * 2048 / 4);
    cvt_f32_bf16<<<4096, 256, 0, stream>>>(W_in, Wbig, 8192 * 2048 / 4);
    cvt_f32_bf16<<<640, 256, 0, stream>>>(W_x, Wx_bf, 160 * 4096 / 4);
    cvt_f32_bf16<<<512, 256, 0, stream>>>(W_dt, Wdt_bf, 4096 * 128 / 4);

    // GEMM1: proj = hidden @ W_in^T -> split h | gate (pipelined, 256 blocks)
    gemm8p<P_SPLIT><<<dim3(256, 1, 1), 512, 0, stream>>>(
        (const short*)hid_bf, (const short*)Wbig, h_buf, gate, 8192, 2048, 2048);

    conv_silu<<<16384, 256, 0, stream>>>(h_buf, conv_w, conv_b, hc_f, hc_bf);

    cvt_f32_bf16<<<2048, 256, 0, stream>>>(W_out, Wbig, 2048 * 4096 / 4);

    gemm_bt<128, EPI_ATOMIC><<<dim3(2, 8, 16), 256, 0, stream>>>(
        (const short*)hc_bf, (const short*)Wx_bf, ssmp, nullptr, nullptr,
        1024, 160, 4096, 160, 256);

    cvt_ts<<<128, 256, 0, stream>>>(ssmp, ts_bf);

    gemm_bt<128, EPI_SOFTPLUS><<<dim3(32, 8, 1), 256, 0, stream>>>(
        (const short*)ts_bf, (const short*)Wdt_bf, h_buf, nullptr, b_dt,
        1024, 4096, 128, 4096, 128);

    scan_p1<<<NCH * 16, 256, 0, stream>>>(h_buf, hc_f, ssmp, A_log, Sbuf, dtsum);
    scan_p2<<<256, 256, 0, stream>>>(A_log, dtsum, Sbuf);
    scan_p3<<<NCH * 16, 256, 0, stream>>>(h_buf, hc_f, ssmp, A_log, D_p, gate, Sbuf, y_bf);

    // GEMM4: out = y @ W_out^T (pipelined, split-K=4, atomic f32 accumulate)
    gemm8p<P_ATOMIC><<<dim3(64, 1, 4), 512, 0, stream>>>(
        (const short*)y_bf, (const short*)Wbig, out, nullptr, 2048, 4096, 1024);
}